// Round 1
// baseline (698.941 us; speedup 1.0000x reference)
//
#include <hip/hip_runtime.h>
#include <hip/hip_bf16.h>

// LocalGNN forward: out = [x, h1, h2, h3] @ W^T + b, h_{k+1} = (D (G+I) D) h_k
// B=4, N=4096, DIM=64, DEPTH=3. fp32 in/out, bf16 MFMA internally (2% rel tol).

typedef __attribute__((ext_vector_type(4))) float  floatx4;
typedef __attribute__((ext_vector_type(8))) short  short8;

#define NB 4
#define NN 4096
#define ND 64
#define KSPLIT 4
#define HSZ ((size_t)NB * NN * ND)   // elements in one h buffer

__device__ __forceinline__ unsigned short f2bf_bits(float v) {
    __hip_bfloat16 b = __float2bfloat16(v);
    return *reinterpret_cast<unsigned short*>(&b);
}

__device__ __forceinline__ short8 pack8(floatx4 a, floatx4 b) {
    short8 r;
    r[0] = (short)f2bf_bits(a[0]); r[1] = (short)f2bf_bits(a[1]);
    r[2] = (short)f2bf_bits(a[2]); r[3] = (short)f2bf_bits(a[3]);
    r[4] = (short)f2bf_bits(b[0]); r[5] = (short)f2bf_bits(b[1]);
    r[6] = (short)f2bf_bits(b[2]); r[7] = (short)f2bf_bits(b[3]);
    return r;
}

// ---------------------------------------------------------------- rowsum -> dinv
// one block per (b, i) row; dinv = 1/(sqrt(rowsum + 1) + 1e-7)
__global__ void rowsum_kernel(const float* __restrict__ graph, float* __restrict__ dinv) {
    int row = blockIdx.x;                       // 0 .. NB*NN-1
    const float* g = graph + (size_t)row * NN;
    int t = threadIdx.x;
    float s = 0.f;
#pragma unroll
    for (int q = 0; q < 4; ++q) {
        floatx4 v = *reinterpret_cast<const floatx4*>(g + q * 1024 + t * 4);
        s += v[0] + v[1] + v[2] + v[3];
    }
#pragma unroll
    for (int off = 32; off > 0; off >>= 1) s += __shfl_down(s, off);
    __shared__ float wsum[4];
    if ((t & 63) == 0) wsum[t >> 6] = s;
    __syncthreads();
    if (t == 0) {
        float tot = wsum[0] + wsum[1] + wsum[2] + wsum[3] + 1.0f;  // +1 self loop
        dinv[row] = 1.0f / (sqrtf(tot) + 1e-7f);
    }
}

// ---------------------------------------------------------------- cast+transpose
// src fp32 [b][NN][ND]  ->  hT bf16 [b][ND][NN]
__global__ void castT_kernel(const float* __restrict__ src, unsigned short* __restrict__ hT) {
    __shared__ float tile[64][65];
    int b = blockIdx.y, row0 = blockIdx.x * 64;
    size_t base = ((size_t)b * NN + row0) * ND;
#pragma unroll
    for (int qi = 0; qi < 16; ++qi) {
        int idx = qi * 256 + threadIdx.x;       // 0..4095
        tile[idx >> 6][idx & 63] = src[base + idx];
    }
    __syncthreads();
#pragma unroll
    for (int qi = 0; qi < 16; ++qi) {
        int idx = qi * 256 + threadIdx.x;
        int n = idx >> 6, r = idx & 63;
        hT[((size_t)b * ND + n) * NN + row0 + r] = f2bf_bits(tile[r][n]);
    }
}

// ---------------------------------------------------------------- propagation GEMM
// P[ks][b][i][n] = sum_{j in ks-quarter} graph[b][i][j] * dinv[b][j] * h[b][j][n]
// wave = 16 rows x 64 cols, mfma_f32_16x16x32_bf16, no LDS.
__global__ __launch_bounds__(256) void prop_gemm(const float* __restrict__ graph,
                                                 const float* __restrict__ dinv,
                                                 const unsigned short* __restrict__ hT,
                                                 float* __restrict__ P) {
    int wid  = blockIdx.x * 4 + (threadIdx.x >> 6);   // 0..4095
    int lane = threadIdx.x & 63;
    int b    = wid >> 10;
    int rem  = wid & 1023;
    int ks   = rem >> 8;                              // K-split quarter
    int mt   = rem & 255;
    int row0 = mt * 16;
    int m = lane & 15, q = lane >> 4;

    const float*          Arow = graph + ((size_t)b * NN + row0 + m) * NN;
    const float*          dv   = dinv + b * NN;
    const unsigned short* Bt   = hT + (size_t)b * ND * NN;

    floatx4 acc0 = {0.f,0.f,0.f,0.f}, acc1 = acc0, acc2 = acc0, acc3 = acc0;

    int k0 = ks * (NN / KSPLIT);
#pragma unroll 2
    for (int kk = 0; kk < NN / KSPLIT; kk += 32) {
        int ka = k0 + kk + q * 8;
        floatx4 a0 = *reinterpret_cast<const floatx4*>(Arow + ka);
        floatx4 a1 = *reinterpret_cast<const floatx4*>(Arow + ka + 4);
        floatx4 d0 = *reinterpret_cast<const floatx4*>(dv + ka);
        floatx4 d1 = *reinterpret_cast<const floatx4*>(dv + ka + 4);
        short8 af = pack8(a0 * d0, a1 * d1);
        short8 b0 = *reinterpret_cast<const short8*>(Bt + (size_t)(0 * 16 + m) * NN + ka);
        short8 b1 = *reinterpret_cast<const short8*>(Bt + (size_t)(1 * 16 + m) * NN + ka);
        short8 b2 = *reinterpret_cast<const short8*>(Bt + (size_t)(2 * 16 + m) * NN + ka);
        short8 b3 = *reinterpret_cast<const short8*>(Bt + (size_t)(3 * 16 + m) * NN + ka);
        acc0 = __builtin_amdgcn_mfma_f32_16x16x32_bf16(af, b0, acc0, 0, 0, 0);
        acc1 = __builtin_amdgcn_mfma_f32_16x16x32_bf16(af, b1, acc1, 0, 0, 0);
        acc2 = __builtin_amdgcn_mfma_f32_16x16x32_bf16(af, b2, acc2, 0, 0, 0);
        acc3 = __builtin_amdgcn_mfma_f32_16x16x32_bf16(af, b3, acc3, 0, 0, 0);
    }

    size_t outb = ((size_t)ks * NB + b) * (NN * ND);
    floatx4* accs[4] = {&acc0, &acc1, &acc2, &acc3};
#pragma unroll
    for (int c = 0; c < 4; ++c)
#pragma unroll
        for (int r = 0; r < 4; ++r) {
            int row = row0 + q * 4 + r;
            P[outb + (size_t)row * ND + c * 16 + m] = (*accs[c])[r];
        }
}

// ---------------------------------------------------------------- combine partials
// hout = d_i*(P0+P1+P2+P3) + d_i^2*hin ; also emit hT bf16 for next step.
__global__ void prep_kernel(const float* __restrict__ P, const float* __restrict__ hin,
                            const float* __restrict__ dinv, float* __restrict__ hout,
                            unsigned short* __restrict__ hT) {
    __shared__ float tile[64][65];
    int b = blockIdx.y, row0 = blockIdx.x * 64;
    size_t base = ((size_t)b * NN + row0) * ND;
    const size_t SZ = HSZ;
#pragma unroll
    for (int qi = 0; qi < 16; ++qi) {
        int idx = qi * 256 + threadIdx.x;
        int r = idx >> 6, n = idx & 63;
        size_t off = base + idx;
        float s = P[off] + P[SZ + off] + P[2 * SZ + off] + P[3 * SZ + off];
        float d = dinv[b * NN + row0 + r];
        float v = d * s + d * d * hin[off];
        hout[off] = v;
        tile[r][n] = v;
    }
    __syncthreads();
#pragma unroll
    for (int qi = 0; qi < 16; ++qi) {
        int idx = qi * 256 + threadIdx.x;
        int n = idx >> 6, r = idx & 63;
        hT[((size_t)b * ND + n) * NN + row0 + r] = f2bf_bits(tile[r][n]);
    }
}

// ---------------------------------------------------------------- final linear
// out[b][i][n] = bias[n] + sum_p sum_{k<64} hp[b][i][k] * W[n][p*64+k]
__global__ __launch_bounds__(256) void final_linear(const float* __restrict__ x,
                                                    const float* __restrict__ h1,
                                                    const float* __restrict__ h2,
                                                    const float* __restrict__ h3,
                                                    const float* __restrict__ W,
                                                    const float* __restrict__ bias,
                                                    float* __restrict__ out) {
    int wid  = blockIdx.x * 4 + (threadIdx.x >> 6);   // 0..1023
    int lane = threadIdx.x & 63;
    int b = wid >> 8;
    int row0 = (wid & 255) * 16;
    int m = lane & 15, q = lane >> 4;

    const float* hs[4] = {x, h1, h2, h3};
    floatx4 acc0 = {0.f,0.f,0.f,0.f}, acc1 = acc0, acc2 = acc0, acc3 = acc0;

#pragma unroll
    for (int p = 0; p < 4; ++p) {
        const float* A = hs[p] + ((size_t)b * NN + row0 + m) * ND;
#pragma unroll
        for (int kk = 0; kk < 64; kk += 32) {
            int ka = kk + q * 8;
            floatx4 a0 = *reinterpret_cast<const floatx4*>(A + ka);
            floatx4 a1 = *reinterpret_cast<const floatx4*>(A + ka + 4);
            short8 af = pack8(a0, a1);
#pragma unroll
            for (int c = 0; c < 4; ++c) {
                const float* Wr = W + (size_t)(c * 16 + m) * 256 + p * 64 + ka;
                floatx4 w0 = *reinterpret_cast<const floatx4*>(Wr);
                floatx4 w1 = *reinterpret_cast<const floatx4*>(Wr + 4);
                short8 bf = pack8(w0, w1);
                switch (c) {
                    case 0: acc0 = __builtin_amdgcn_mfma_f32_16x16x32_bf16(af, bf, acc0, 0, 0, 0); break;
                    case 1: acc1 = __builtin_amdgcn_mfma_f32_16x16x32_bf16(af, bf, acc1, 0, 0, 0); break;
                    case 2: acc2 = __builtin_amdgcn_mfma_f32_16x16x32_bf16(af, bf, acc2, 0, 0, 0); break;
                    case 3: acc3 = __builtin_amdgcn_mfma_f32_16x16x32_bf16(af, bf, acc3, 0, 0, 0); break;
                }
            }
        }
    }
    floatx4* accs[4] = {&acc0, &acc1, &acc2, &acc3};
#pragma unroll
    for (int c = 0; c < 4; ++c) {
        float bb = bias[c * 16 + m];
#pragma unroll
        for (int r = 0; r < 4; ++r) {
            int row = row0 + q * 4 + r;
            out[((size_t)b * NN + row) * ND + c * 16 + m] = (*accs[c])[r] + bb;
        }
    }
}

// ---------------------------------------------------------------- launch
extern "C" void kernel_launch(void* const* d_in, const int* in_sizes, int n_in,
                              void* d_out, int out_size, void* d_ws, size_t ws_size,
                              hipStream_t stream) {
    const float* x     = (const float*)d_in[0];
    const float* graph = (const float*)d_in[1];
    const float* W     = (const float*)d_in[2];
    const float* bias  = (const float*)d_in[3];
    float* out = (float*)d_out;

    // workspace layout
    char* w = (char*)d_ws;
    float*          dinv = (float*)w;                                   //  64 KB
    unsigned short* hT   = (unsigned short*)(w + 65536);                //   2 MB
    float*          P    = (float*)(w + 65536 + 2097152);               //  16 MB (KSPLIT partials)
    float*          h1   = (float*)(w + 65536 + 2097152 + 16777216);    //   4 MB
    float*          h2   = h1 + HSZ;                                    //   4 MB
    float*          h3   = h2 + HSZ;                                    //   4 MB

    rowsum_kernel<<<NB * NN, 256, 0, stream>>>(graph, dinv);
    castT_kernel<<<dim3(NN / 64, NB), 256, 0, stream>>>(x, hT);

    const float* hin = x;
    float* houts[3] = {h1, h2, h3};
    for (int s = 0; s < 3; ++s) {
        prop_gemm<<<1024, 256, 0, stream>>>(graph, dinv, hT, P);
        prep_kernel<<<dim3(NN / 64, NB), 256, 0, stream>>>(P, hin, dinv, houts[s], hT);
        hin = houts[s];
    }
    final_linear<<<256, 256, 0, stream>>>(x, h1, h2, h3, W, bias, out);
}

// Round 2
// 560.839 us; speedup vs baseline: 1.2462x; 1.2462x over previous
//
#include <hip/hip_runtime.h>
#include <hip/hip_bf16.h>

// LocalGNN forward: out = [x, h1, h2, h3] @ W^T + b, h_{k+1} = Ghat h_k,
// Ghat = D (G+I) D materialized once in bf16. B=4, N=4096, DIM=64.

typedef __attribute__((ext_vector_type(4))) float  floatx4;
typedef __attribute__((ext_vector_type(8))) short  short8;

#define NB 4
#define NN 4096
#define ND 64
#define KSPLIT 4
#define HSZ ((size_t)NB * NN * ND)

__device__ __forceinline__ unsigned short f2bf_bits(float v) {
    __hip_bfloat16 b = __float2bfloat16(v);
    return *reinterpret_cast<unsigned short*>(&b);
}

__device__ __forceinline__ short8 pack8(floatx4 a, floatx4 b) {
    short8 r;
    r[0] = (short)f2bf_bits(a[0]); r[1] = (short)f2bf_bits(a[1]);
    r[2] = (short)f2bf_bits(a[2]); r[3] = (short)f2bf_bits(a[3]);
    r[4] = (short)f2bf_bits(b[0]); r[5] = (short)f2bf_bits(b[1]);
    r[6] = (short)f2bf_bits(b[2]); r[7] = (short)f2bf_bits(b[3]);
    return r;
}

// ---------------------------------------------------------------- rowsum -> dinv
__global__ void rowsum_kernel(const float* __restrict__ graph, float* __restrict__ dinv) {
    int row = blockIdx.x;                       // 0 .. NB*NN-1
    const float* g = graph + (size_t)row * NN;
    int t = threadIdx.x;
    float s = 0.f;
#pragma unroll
    for (int q = 0; q < 4; ++q) {
        floatx4 v = *reinterpret_cast<const floatx4*>(g + q * 1024 + t * 4);
        s += v[0] + v[1] + v[2] + v[3];
    }
#pragma unroll
    for (int off = 32; off > 0; off >>= 1) s += __shfl_down(s, off);
    __shared__ float wsum[4];
    if ((t & 63) == 0) wsum[t >> 6] = s;
    __syncthreads();
    if (t == 0) {
        float tot = wsum[0] + wsum[1] + wsum[2] + wsum[3] + 1.0f;  // +1 self loop
        dinv[row] = 1.0f / (sqrtf(tot) + 1e-7f);
    }
}

// ---------------------------------------------------------------- ghat = (G+I) D D -> bf16
// 16 elements per thread, fully coalesced stream.
__global__ void make_ghat(const float* __restrict__ g, const float* __restrict__ dinv,
                          unsigned short* __restrict__ ghat) {
    size_t e = ((size_t)blockIdx.x * 256 + threadIdx.x) * 16;
    int ig = (int)(e >> 12);          // global row 0..16383
    int b  = ig >> 12;
    int i  = ig & 4095;
    int j0 = (int)(e & 4095);
    float di = dinv[ig];
    const float* dj = dinv + (size_t)b * NN + j0;
    const float* gp = g + e;
    floatx4 v[4], d[4];
#pragma unroll
    for (int q = 0; q < 4; ++q) {
        v[q] = *reinterpret_cast<const floatx4*>(gp + q * 4);
        d[q] = *reinterpret_cast<const floatx4*>(dj + q * 4);
    }
    if (i >= j0 && i < j0 + 16) {                 // self loop on diagonal
        float* vf = (float*)v;
        vf[i - j0] += 1.0f;
    }
#pragma unroll
    for (int q = 0; q < 4; ++q) v[q] = v[q] * d[q] * di;
    short8 o0 = pack8(v[0], v[1]);
    short8 o1 = pack8(v[2], v[3]);
    *reinterpret_cast<short8*>(ghat + e)     = o0;
    *reinterpret_cast<short8*>(ghat + e + 8) = o1;
}

// ---------------------------------------------------------------- cast+transpose x -> hT
__global__ void castT_kernel(const float* __restrict__ src, unsigned short* __restrict__ hT) {
    __shared__ float tile[64][65];
    int b = blockIdx.y, row0 = blockIdx.x * 64;
    size_t base = ((size_t)b * NN + row0) * ND;
#pragma unroll
    for (int qi = 0; qi < 16; ++qi) {
        int idx = qi * 256 + threadIdx.x;
        tile[idx >> 6][idx & 63] = src[base + idx];
    }
    __syncthreads();
#pragma unroll
    for (int qi = 0; qi < 16; ++qi) {
        int idx = qi * 256 + threadIdx.x;
        int n = idx >> 6, r = idx & 63;
        hT[((size_t)b * ND + n) * NN + row0 + r] = f2bf_bits(tile[r][n]);
    }
}

// ---------------------------------------------------------------- propagation GEMM
// P[ks][b][i][n] = sum_{j in quarter} ghat[b][i][j] * h[b][j][n]
// block: 128 rows x 64 cols, K-quarter 1024. B staged in padded LDS.
__global__ __launch_bounds__(256) void prop_gemm(const unsigned short* __restrict__ ghat,
                                                 const unsigned short* __restrict__ hT,
                                                 float* __restrict__ P) {
    __shared__ __align__(16) unsigned short Bs[64][72];   // pad: 144B stride, conflict-free
    int bid  = blockIdx.x;              // 512 blocks
    int b    = bid & 3;
    int ks   = (bid >> 2) & 3;
    int mblk = bid >> 4;                // 0..31
    int w    = threadIdx.x >> 6;
    int lane = threadIdx.x & 63;
    int m = lane & 15, q = lane >> 4;
    int row0 = mblk * 128 + w * 32;
    int k0 = ks * 1024;

    const unsigned short* A0 = ghat + (size_t)b * NN * NN + (size_t)(row0 + m) * NN + k0 + q * 8;
    const unsigned short* A1 = A0 + (size_t)16 * NN;

    int t = threadIdx.x;
    int sn = t >> 2, sk = (t & 3) * 16;
    const unsigned short* src = hT + (size_t)b * ND * NN + (size_t)sn * NN + k0 + sk;

    floatx4 acc[2][4];
#pragma unroll
    for (int mt = 0; mt < 2; ++mt)
#pragma unroll
        for (int c = 0; c < 4; ++c) acc[mt][c] = (floatx4){0.f, 0.f, 0.f, 0.f};

    short8 v0 = *reinterpret_cast<const short8*>(src);
    short8 v1 = *reinterpret_cast<const short8*>(src + 8);

    for (int kk = 0; kk < 1024; kk += 64) {
        __syncthreads();
        *reinterpret_cast<short8*>(&Bs[sn][sk])     = v0;
        *reinterpret_cast<short8*>(&Bs[sn][sk + 8]) = v1;
        __syncthreads();
        if (kk + 64 < 1024) {                       // prefetch next B slice
            src += 64;
            v0 = *reinterpret_cast<const short8*>(src);
            v1 = *reinterpret_cast<const short8*>(src + 8);
        }
#pragma unroll
        for (int ki = 0; ki < 2; ++ki) {
            short8 a0 = *reinterpret_cast<const short8*>(A0 + kk + ki * 32);
            short8 a1 = *reinterpret_cast<const short8*>(A1 + kk + ki * 32);
#pragma unroll
            for (int c = 0; c < 4; ++c) {
                short8 bf = *reinterpret_cast<const short8*>(&Bs[c * 16 + m][ki * 32 + q * 8]);
                acc[0][c] = __builtin_amdgcn_mfma_f32_16x16x32_bf16(a0, bf, acc[0][c], 0, 0, 0);
                acc[1][c] = __builtin_amdgcn_mfma_f32_16x16x32_bf16(a1, bf, acc[1][c], 0, 0, 0);
            }
        }
    }

    float* pout = P + ((size_t)ks * NB + b) * ((size_t)NN * ND);
#pragma unroll
    for (int mt = 0; mt < 2; ++mt)
#pragma unroll
        for (int c = 0; c < 4; ++c)
#pragma unroll
            for (int r = 0; r < 4; ++r) {
                int row = row0 + mt * 16 + q * 4 + r;
                pout[(size_t)row * ND + c * 16 + m] = acc[mt][c][r];
            }
}

// ---------------------------------------------------------------- combine partials
// h = P0+P1+P2+P3 ; emit bf16 row-major (for final) + bf16 transposed (next step B).
__global__ void prep_kernel(const float* __restrict__ P,
                            unsigned short* __restrict__ hrow,
                            unsigned short* __restrict__ hT) {
    __shared__ float tile[64][65];
    int b = blockIdx.y, row0 = blockIdx.x * 64;
    size_t base = ((size_t)b * NN + row0) * ND;
    const size_t SZ = HSZ;
#pragma unroll
    for (int qi = 0; qi < 16; ++qi) {
        int idx = qi * 256 + threadIdx.x;
        int r = idx >> 6, n = idx & 63;
        size_t off = base + idx;
        float s = P[off] + P[SZ + off] + P[2 * SZ + off] + P[3 * SZ + off];
        hrow[off] = f2bf_bits(s);
        tile[r][n] = s;
    }
    __syncthreads();
#pragma unroll
    for (int qi = 0; qi < 16; ++qi) {
        int idx = qi * 256 + threadIdx.x;
        int n = idx >> 6, r = idx & 63;
        hT[((size_t)b * ND + n) * NN + row0 + r] = f2bf_bits(tile[r][n]);
    }
}

// ---------------------------------------------------------------- final linear
__global__ __launch_bounds__(256) void final_linear(const float* __restrict__ x,
                                                    const unsigned short* __restrict__ h1,
                                                    const unsigned short* __restrict__ h2,
                                                    const unsigned short* __restrict__ h3,
                                                    const float* __restrict__ W,
                                                    const float* __restrict__ bias,
                                                    float* __restrict__ out) {
    int wid  = blockIdx.x * 4 + (threadIdx.x >> 6);   // 0..1023
    int lane = threadIdx.x & 63;
    int b = wid >> 8;
    int row0 = (wid & 255) * 16;
    int m = lane & 15, q = lane >> 4;

    floatx4 acc[4];
#pragma unroll
    for (int c = 0; c < 4; ++c) acc[c] = (floatx4){0.f, 0.f, 0.f, 0.f};

    // p = 0 : x (fp32, pack in-kernel)
    {
        const float* A = x + ((size_t)b * NN + row0 + m) * ND;
#pragma unroll
        for (int ki = 0; ki < 2; ++ki) {
            floatx4 a0 = *reinterpret_cast<const floatx4*>(A + ki * 32 + q * 8);
            floatx4 a1 = *reinterpret_cast<const floatx4*>(A + ki * 32 + q * 8 + 4);
            short8 af = pack8(a0, a1);
#pragma unroll
            for (int c = 0; c < 4; ++c) {
                const float* Wr = W + (size_t)(c * 16 + m) * 256 + ki * 32 + q * 8;
                short8 bf = pack8(*reinterpret_cast<const floatx4*>(Wr),
                                  *reinterpret_cast<const floatx4*>(Wr + 4));
                acc[c] = __builtin_amdgcn_mfma_f32_16x16x32_bf16(af, bf, acc[c], 0, 0, 0);
            }
        }
    }
    // p = 1..3 : h bf16 direct
    const unsigned short* hs[3] = {h1, h2, h3};
#pragma unroll
    for (int p = 1; p < 4; ++p) {
        const unsigned short* A = hs[p - 1] + ((size_t)b * NN + row0 + m) * ND;
#pragma unroll
        for (int ki = 0; ki < 2; ++ki) {
            short8 af = *reinterpret_cast<const short8*>(A + ki * 32 + q * 8);
#pragma unroll
            for (int c = 0; c < 4; ++c) {
                const float* Wr = W + (size_t)(c * 16 + m) * 256 + p * 64 + ki * 32 + q * 8;
                short8 bf = pack8(*reinterpret_cast<const floatx4*>(Wr),
                                  *reinterpret_cast<const floatx4*>(Wr + 4));
                acc[c] = __builtin_amdgcn_mfma_f32_16x16x32_bf16(af, bf, acc[c], 0, 0, 0);
            }
        }
    }
#pragma unroll
    for (int c = 0; c < 4; ++c) {
        float bb = bias[c * 16 + m];
#pragma unroll
        for (int r = 0; r < 4; ++r) {
            int row = row0 + q * 4 + r;
            out[((size_t)b * NN + row) * ND + c * 16 + m] = acc[c][r] + bb;
        }
    }
}

// ---------------------------------------------------------------- launch
extern "C" void kernel_launch(void* const* d_in, const int* in_sizes, int n_in,
                              void* d_out, int out_size, void* d_ws, size_t ws_size,
                              hipStream_t stream) {
    const float* x     = (const float*)d_in[0];
    const float* graph = (const float*)d_in[1];
    const float* W     = (const float*)d_in[2];
    const float* bias  = (const float*)d_in[3];
    float* out = (float*)d_out;

    // workspace layout (bytes)
    char* w = (char*)d_ws;
    float*          dinv = (float*)w;                                    //  64 KB
    unsigned short* hT   = (unsigned short*)(w + (1 << 16));             //   2 MB
    unsigned short* ghat = (unsigned short*)(w + (1 << 16) + (1 << 21)); // 128 MB
    char* w2 = w + (1 << 16) + (1 << 21) + ((size_t)NB * NN * NN * 2);
    float*          P    = (float*)w2;                                   //  16 MB
    unsigned short* h1   = (unsigned short*)(w2 + KSPLIT * HSZ * 4);
    unsigned short* h2   = h1 + HSZ;
    unsigned short* h3   = h2 + HSZ;

    rowsum_kernel<<<NB * NN, 256, 0, stream>>>(graph, dinv);
    make_ghat<<<(NB * NN * NN) / (256 * 16), 256, 0, stream>>>(graph, dinv, ghat);
    castT_kernel<<<dim3(NN / 64, NB), 256, 0, stream>>>(x, hT);

    unsigned short* houts[3] = {h1, h2, h3};
    for (int s = 0; s < 3; ++s) {
        prop_gemm<<<512, 256, 0, stream>>>(ghat, hT, P);
        prep_kernel<<<dim3(NN / 64, NB), 256, 0, stream>>>(P, houts[s], hT);
    }
    final_linear<<<256, 256, 0, stream>>>(x, h1, h2, h3, W, bias, out);
}